// Round 11
// baseline (10648.684 us; speedup 1.0000x reference)
//
#include <hip/hip_runtime.h>

typedef __attribute__((ext_vector_type(8))) short short8;
typedef __attribute__((ext_vector_type(4))) float f32x4;
typedef __attribute__((ext_vector_type(4))) int int4v;
typedef __attribute__((ext_vector_type(4))) unsigned short u16x4;
typedef unsigned short u16;

#define T_LEN 256
#define BATCH 64
#define HID   1024
#define GDIM  4128
#define BH    65536

__device__ __forceinline__ u16 f2bf(float f){
  unsigned u = __builtin_bit_cast(unsigned, f);
  return (u16)((u + 0x7fffu + ((u >> 16) & 1u)) >> 16);
}

// ---- prologue kernels -------------------------------------------------------

__global__ __launch_bounds__(1024) void repackW(const float* __restrict__ Wih,
                                                const float* __restrict__ Whh,
                                                u16* __restrict__ Wt)
{
  __shared__ float tile[32][33];
  int k = blockIdx.x * 32 + threadIdx.y;
  int c = blockIdx.y * 32 + threadIdx.x;
  float v = (k < 1024) ? Wih[(size_t)k * GDIM + c]
                       : Whh[(size_t)(k - 1024) * GDIM + c];
  tile[threadIdx.y][threadIdx.x] = v;
  __syncthreads();
  int c2 = blockIdx.y * 32 + threadIdx.y;
  int k2 = blockIdx.x * 32 + threadIdx.x;
  Wt[(size_t)c2 * 2048 + k2] = f2bf(tile[threadIdx.x][threadIdx.y]);
}

__global__ __launch_bounds__(256) void gatherX(const int* __restrict__ tokens,
                                               const float* __restrict__ emb,
                                               u16* __restrict__ x,
                                               float* __restrict__ maskout)
{
  int idx = blockIdx.x;
  int tok = tokens[idx];
  const f32x4* src = (const f32x4*)&emb[(size_t)tok * HID];
  f32x4 v = src[threadIdx.x];
  u16x4 o;
  #pragma unroll
  for (int j = 0; j < 4; ++j) o[j] = f2bf(v[j]);
  *(u16x4*)&x[(size_t)idx * HID + threadIdx.x * 4] = o;
  if (threadIdx.x == 0) maskout[idx] = (tok != 0) ? 1.0f : 0.0f;
}

__global__ __launch_bounds__(256) void biasK(const float* __restrict__ bih0, const float* __restrict__ bhh0,
                                             const float* __restrict__ bih1, const float* __restrict__ bhh1,
                                             float* __restrict__ bias0, float* __restrict__ bias1)
{
  int i = blockIdx.x * 256 + threadIdx.x;
  if (i < GDIM){ bias0[i] = bih0[i] + bhh0[i]; bias1[i] = bih1[i] + bhh1[i]; }
}

__global__ __launch_bounds__(256) void zeroK(int4v* __restrict__ p)
{
  int4v z = {0,0,0,0};
  p[blockIdx.x * 256 + threadIdx.x] = z;
}

// ---- per-step fused kernel --------------------------------------------------
// One dispatch per step s (kernel boundary = the barrier; CP handles drain +
// cross-XCD coherence). 256 WGs x 512 thr, 1 WG/CU. WG w: lay = w>>7, owns
// h-elems E0..E0+7 (E0=(w&127)*8). L0 computes t=s (A = x[s], h1[s-1]);
// L1 computes t=s-1 (A = h1[s-1], h2[s-2]) -- all inputs from EARLIER
// dispatches only. Rest cols (32 x K=2048) staged to LDS each dispatch
// (L2-resident slice, XCD-stable); sm cols (0..31) direct from L2.
// Gates never leave the WG; c-state in global f32 (same CU every dispatch).
__global__ __launch_bounds__(512, 1) void step(
    const u16* __restrict__ Wt0, const u16* __restrict__ Wt1,
    const float* __restrict__ bias0, const float* __restrict__ bias1,
    const u16* __restrict__ x, u16* __restrict__ hA, u16* __restrict__ hB,
    const u16* __restrict__ zerob, float* __restrict__ c0,
    float* __restrict__ c1, float* __restrict__ out, int s)
{
  __shared__ __align__(16) u16 Ws[32 * 2048];      // 128KB rest weights
  __shared__ __align__(16) float smT[32 * 68];     // sm logits, [col][row]
  __shared__ __align__(16) float restT[32 * 68];   // rest gates, [col][row]
  __shared__ __align__(16) u16 hStage[64 * 8];     // bf16 h, [row][elem]
  __shared__ __align__(16) float oStage[64 * 8];   // f32 h2, [row][elem]

  const int wg = blockIdx.x, tid = threadIdx.x;
  const int lane = tid & 63, wave = tid >> 6;
  const int lo = lane & 15, hi = lane >> 4, khi = hi * 8;
  const int nw = wave & 1, mt = wave >> 1;         // 4 M-tiles x 2 tile-groups
  const int row = mt * 16 + lo;
  const int lay = wg >> 7;
  const int E0 = (wg & 127) * 8;
  const int t = lay ? (s - 1) : s;
  if (t < 0 || t >= T_LEN) return;                 // uniform per WG

  const u16* Wt = lay ? Wt1 : Wt0;
  const float* bias = lay ? bias1 : bias0;

  auto gcol = [&](int c){ return 32 + (c >> 3) * 1024 + E0 + (c & 7); };

  // stage rest cols: 32 x K=2048, XOR-swizzled (16B-preserving)
  for (int i = tid; i < 32 * 256; i += 512){
    int c = i >> 8, ck = (i & 255) << 3;
    *(int4v*)&Ws[c * 2048 + (ck ^ ((c & 7) << 3))] =
        *(const int4v*)&Wt[(size_t)gcol(c) * 2048 + ck];
  }

  // per-wave tiles: nw=0 -> sm cols {lo,16+lo} (global B); nw=1 -> rest (LDS)
  float bv0, bv1;
  const u16 *gB0 = nullptr, *gB1 = nullptr;
  if (nw == 0){
    bv0 = bias[lo]; bv1 = bias[16 + lo];
    gB0 = Wt + (size_t)lo * 2048;
    gB1 = Wt + (size_t)(16 + lo) * 2048;
  } else {
    bv0 = bias[gcol(lo)]; bv1 = bias[gcol(16 + lo)];
  }
  __syncthreads();

  auto ldsB = [&](int c, int k)->short8 {
    return *(const short8*)&Ws[c * 2048 + (k ^ ((c & 7) << 3))];
  };

  // matmul over one K=1024 half: A from Asrc (1024-wide rows), B k-offset kw.
  // Straight-line unroll, all indices compile-time (rule #20).
  auto mm = [&](const u16* Asrc, int kw, f32x4& r0, f32x4& r1){
    const u16* pA = Asrc + (size_t)row * HID;
    if (nw == 0){
      #pragma unroll
      for (int i = 0; i < 32; ++i){
        int k = kw + i * 32 + khi;
        short8 a = *(const short8*)(pA + i * 32 + khi);
        r0 = __builtin_amdgcn_mfma_f32_16x16x32_bf16(a, *(const short8*)(gB0 + k), r0, 0,0,0);
        r1 = __builtin_amdgcn_mfma_f32_16x16x32_bf16(a, *(const short8*)(gB1 + k), r1, 0,0,0);
      }
    } else {
      #pragma unroll
      for (int i = 0; i < 32; ++i){
        int k = kw + i * 32 + khi;
        short8 a = *(const short8*)(pA + i * 32 + khi);
        r0 = __builtin_amdgcn_mfma_f32_16x16x32_bf16(a, ldsB(lo, k), r0, 0,0,0);
        r1 = __builtin_amdgcn_mfma_f32_16x16x32_bf16(a, ldsB(16 + lo, k), r1, 0,0,0);
      }
    }
  };

  // A sources (all from earlier dispatches)
  const u16* pIH = lay ? (hA + (size_t)t * BH) : (x + (size_t)t * BH);
  const u16* pHH = (t == 0) ? zerob
                 : (lay ? (hB + (size_t)(t - 1) * BH) : (hA + (size_t)(t - 1) * BH));

  f32x4 a0 = {bv0, bv0, bv0, bv0}, a1 = {bv1, bv1, bv1, bv1};
  mm(pIH, 0, a0, a1);
  mm(pHH, 1024, a0, a1);

  // transpose acc -> per-row layout (C/D: col=lane&15, row=(lane>>4)*4+j)
  const int r0i = mt * 16 + hi * 4;
  if (nw == 0){
    *(f32x4*)&smT[lo * 68 + r0i] = a0;
    *(f32x4*)&smT[(16 + lo) * 68 + r0i] = a1;
  } else {
    *(f32x4*)&restT[lo * 68 + r0i] = a0;
    *(f32x4*)&restT[(16 + lo) * 68 + r0i] = a1;
  }
  __syncthreads();

  // gating: thread -> (row r, elem E0+j); c-state in global f32
  {
    const int r = tid >> 3, j = tid & 7;
    const int n = (wg & 127) >> 3;
    float m1 = -1e30f, m2 = -1e30f;
    float l1[16], l2[16];
    #pragma unroll
    for (int i = 0; i < 16; ++i){
      l1[i] = smT[i * 68 + r]; l2[i] = smT[(16 + i) * 68 + r];
      m1 = fmaxf(m1, l1[i]);   m2 = fmaxf(m2, l2[i]);
    }
    float s1 = 0.f, s2 = 0.f, cu1 = 0.f, cu2 = 0.f;
    #pragma unroll
    for (int i = 0; i < 16; ++i){
      float e1 = __expf(l1[i] - m1), e2 = __expf(l2[i] - m2);
      s1 += e1; s2 += e2;
      if (i <= n){ cu1 += e1; cu2 += e2; }
    }
    const float cin = 1.f - cu1 / s1;
    const float cf  = cu2 / s2;
    const float ov  = cf * cin;
    const float og = restT[j * 68 + r];
    const float ce = restT[(8 + j) * 68 + r];
    const float ig = restT[(16 + j) * 68 + r];
    const float fg = restT[(24 + j) * 68 + r];
    const float ogv = 1.f / (1.f + __expf(-og));
    const float inv = 1.f / (1.f + __expf(-ig));
    const float fgv = 1.f / (1.f + __expf(-fg));
    const float cev = tanhf(ce);
    float* cp = (lay ? c1 : c0) + r * HID + E0 + j;
    const float cx = (t == 0) ? 0.f : *cp;
    const float fga = fgv * ov + (cf - ov);
    const float iga = inv * ov + (cin - ov);
    const float cy  = fga * cx + iga * cev;
    *cp = cy;
    const float hy = ogv * tanhf(cy);
    hStage[r * 8 + j] = f2bf(hy);
    if (lay) oStage[r * 8 + j] = hy;
  }
  __syncthreads();

  // coalesced stores (plain — kernel boundary provides coherence)
  if (tid < 64){
    int4v hv = *(const int4v*)&hStage[tid * 8];
    u16* dst = (lay ? hB : hA) + (size_t)t * BH + tid * HID + E0;
    *(int4v*)dst = hv;
  } else if (lay && tid < 192){
    int w = tid - 64;
    int r = w >> 1, half = w & 1;
    f32x4 ov4 = *(const f32x4*)&oStage[r * 8 + half * 4];
    *(f32x4*)&out[((size_t)t * BATCH + r) * HID + E0 + half * 4] = ov4;
  }
}

// ---- launch -----------------------------------------------------------------

extern "C" void kernel_launch(void* const* d_in, const int* in_sizes, int n_in,
                              void* d_out, int out_size, void* d_ws, size_t ws_size,
                              hipStream_t stream)
{
  (void)in_sizes; (void)n_in; (void)out_size; (void)ws_size;
  const int*   tokens = (const int*)d_in[0];
  const float* emb    = (const float*)d_in[1];
  const float* Wih0   = (const float*)d_in[2];
  const float* bih0   = (const float*)d_in[3];
  const float* Whh0   = (const float*)d_in[4];
  const float* bhh0   = (const float*)d_in[5];
  const float* Wih1   = (const float*)d_in[6];
  const float* bih1   = (const float*)d_in[7];
  const float* Whh1   = (const float*)d_in[8];
  const float* bhh1   = (const float*)d_in[9];
  float* out = (float*)d_out;

  char* ws = (char*)d_ws;
  u16*   Wt0    = (u16*)(ws);                     // 16,908,288
  u16*   Wt1    = (u16*)(ws + 16908288);          // 16,908,288
  u16*   x      = (u16*)(ws + 33816576);          // 33,554,432
  u16*   hA     = (u16*)(ws + 67371008);          // 33,554,432 (h1 full history)
  u16*   hB     = (u16*)(ws + 100925440);         // 33,554,432 (h2 full history)
  float* bias0  = (float*)(ws + 134479872);       // 16,512
  float* bias1  = (float*)(ws + 134496384);       // 16,512
  float* c0     = (float*)(ws + 134512896);       // 262,144
  float* c1     = (float*)(ws + 134775040);       // 262,144
  u16*   zerob  = (u16*)(ws + 135037184);         // 131,072 (zeroed)
  // total 135,168,256 bytes

  repackW<<<dim3(64,129), dim3(32,32), 0, stream>>>(Wih0, Whh0, Wt0);
  repackW<<<dim3(64,129), dim3(32,32), 0, stream>>>(Wih1, Whh1, Wt1);
  gatherX<<<16384, 256, 0, stream>>>(tokens, emb, x, out + 16777216);
  biasK<<<17, 256, 0, stream>>>(bih0, bhh0, bih1, bhh1, bias0, bias1);
  zeroK<<<32, 256, 0, stream>>>((int4v*)zerob);

  for (int s = 0; s <= T_LEN; ++s)
    step<<<256, 512, 0, stream>>>(Wt0, Wt1, bias0, bias1, x, hA, hB, zerob,
                                  c0, c1, out, s);
}

// Round 12
// 9786.028 us; speedup vs baseline: 1.0882x; 1.0882x over previous
//
#include <hip/hip_runtime.h>

typedef __attribute__((ext_vector_type(8))) short short8;
typedef __attribute__((ext_vector_type(4))) float f32x4;
typedef __attribute__((ext_vector_type(4))) int int4v;
typedef __attribute__((ext_vector_type(4))) unsigned short u16x4;
typedef unsigned short u16;

#define T_LEN 256
#define BATCH 64
#define HID   1024
#define GDIM  4128
#define BH    65536
#define NWG   256

__device__ __forceinline__ u16 f2bf(float f){
  unsigned u = __builtin_bit_cast(unsigned, f);
  return (u16)((u + 0x7fffu + ((u >> 16) & 1u)) >> 16);
}

// VALU-busy filler (~128 cycles, no memory traffic): clock-governor signal.
__device__ __forceinline__ void burn(){
  float a = 1.0f;
  #pragma unroll
  for (int i = 0; i < 64; ++i) a = __builtin_fmaf(a, 1.0000001f, 1e-9f);
  asm volatile("" :: "v"(a));
}

// ---- prologue kernels -------------------------------------------------------

__global__ __launch_bounds__(1024) void repackW(const float* __restrict__ Wih,
                                                const float* __restrict__ Whh,
                                                u16* __restrict__ Wt)
{
  __shared__ float tile[32][33];
  int k = blockIdx.x * 32 + threadIdx.y;
  int c = blockIdx.y * 32 + threadIdx.x;
  float v = (k < 1024) ? Wih[(size_t)k * GDIM + c]
                       : Whh[(size_t)(k - 1024) * GDIM + c];
  tile[threadIdx.y][threadIdx.x] = v;
  __syncthreads();
  int c2 = blockIdx.y * 32 + threadIdx.y;
  int k2 = blockIdx.x * 32 + threadIdx.x;
  Wt[(size_t)c2 * 2048 + k2] = f2bf(tile[threadIdx.x][threadIdx.y]);
}

__global__ __launch_bounds__(256) void gatherX(const int* __restrict__ tokens,
                                               const float* __restrict__ emb,
                                               u16* __restrict__ x,
                                               float* __restrict__ maskout)
{
  int idx = blockIdx.x;
  int tok = tokens[idx];
  const f32x4* src = (const f32x4*)&emb[(size_t)tok * HID];
  f32x4 v = src[threadIdx.x];
  u16x4 o;
  #pragma unroll
  for (int j = 0; j < 4; ++j) o[j] = f2bf(v[j]);
  *(u16x4*)&x[(size_t)idx * HID + threadIdx.x * 4] = o;
  if (threadIdx.x == 0) maskout[idx] = (tok != 0) ? 1.0f : 0.0f;
}

__global__ __launch_bounds__(256) void biasK(const float* __restrict__ bih0, const float* __restrict__ bhh0,
                                             const float* __restrict__ bih1, const float* __restrict__ bhh1,
                                             float* __restrict__ bias0, float* __restrict__ bias1)
{
  int i = blockIdx.x * 256 + threadIdx.x;
  if (i < GDIM){ bias0[i] = bih0[i] + bhh0[i]; bias1[i] = bih1[i] + bhh1[i]; }
}

// ---- fused persistent kernel ------------------------------------------------
// Round-6 structure. 256 WGs x 512 thr, 1 WG/CU. WG w: lay=w>>7, owns h-elems
// E0..E0+7. Rest weights (32 cols x K=2048) LDS-resident; sm cols from L2.
// Epoch s: L0 t=s, L1 t=s-2. ONE barrier/epoch: slot store -> master scans ->
// flag -> wave0 of each WG polls flag UNIFORMLY (whole wave, one address) ->
// LDS mirror releases waves 1-7. All spins VALU-burn; every spin's release
// comes from a DIFFERENT wave or global memory (deadlock-free by audit).
__global__ __launch_bounds__(512, 1) void persist(
    const u16* __restrict__ Wt0, const u16* __restrict__ Wt1,
    const float* __restrict__ bias0, const float* __restrict__ bias1,
    const u16* __restrict__ x, u16* __restrict__ hA, u16* __restrict__ hB,
    float* __restrict__ out, unsigned* __restrict__ slots,
    unsigned* __restrict__ flag)
{
  __shared__ __align__(16) u16 Ws[32 * 2048];      // 128KB rest weights (ih+hh)
  __shared__ __align__(16) float smT[32 * 68];     // sm logits, [col][row]
  __shared__ __align__(16) float restT[32 * 68];   // rest gates, [col][row]
  __shared__ __align__(16) u16 hStage[64 * 8];     // bf16 h, [row][elem]
  __shared__ __align__(16) float oStage[64 * 8];   // f32 h2, [row][elem]
  __shared__ unsigned lflag;                       // intra-WG release mirror

  const int wg = blockIdx.x, tid = threadIdx.x;
  const int lane = tid & 63, wave = tid >> 6;
  const int lo = lane & 15, hi = lane >> 4, khi = hi * 8;
  const int nw = wave & 1, mt = wave >> 1;
  const int row = mt * 16 + lo;
  const int lay = wg >> 7;
  const int E0 = (wg & 127) * 8;
  const u16* Wt = lay ? Wt1 : Wt0;
  const float* bias = lay ? bias1 : bias0;

  auto gcol = [&](int c){ return 32 + (c >> 3) * 1024 + E0 + (c & 7); };

  if (tid == 0) lflag = 0;
  // one-time staging: 32 rest cols x K=2048, XOR-swizzled (16B-preserving)
  for (int i = tid; i < 32 * 256; i += 512){
    int c = i >> 8, ck = (i & 255) << 3;
    *(int4v*)&Ws[c * 2048 + (ck ^ ((c & 7) << 3))] =
        *(const int4v*)&Wt[(size_t)gcol(c) * 2048 + ck];
  }

  float bv0, bv1;
  const u16 *gB0 = nullptr, *gB1 = nullptr;
  if (nw == 0){
    bv0 = bias[lo]; bv1 = bias[16 + lo];
    gB0 = Wt + (size_t)lo * 2048;
    gB1 = Wt + (size_t)(16 + lo) * 2048;
  } else {
    bv0 = bias[gcol(lo)]; bv1 = bias[gcol(16 + lo)];
  }
  __syncthreads();

  auto ldsB = [&](int c, int k)->short8 {
    return *(const short8*)&Ws[c * 2048 + (k ^ ((c & 7) << 3))];
  };

  // matmul: straight-line full unroll, all indices compile-time (rule #20).
  auto mm = [&](const u16* Asrc, int koff, f32x4& r0, f32x4& r1){
    const u16* pA = Asrc + (size_t)row * HID;
    if (nw == 0){
      #pragma unroll
      for (int i = 0; i < 32; ++i){
        int k = koff + i * 32 + khi;
        short8 a = *(const short8*)(pA + i * 32 + khi);
        r0 = __builtin_amdgcn_mfma_f32_16x16x32_bf16(a, *(const short8*)(gB0 + k), r0, 0,0,0);
        r1 = __builtin_amdgcn_mfma_f32_16x16x32_bf16(a, *(const short8*)(gB1 + k), r1, 0,0,0);
      }
    } else {
      #pragma unroll
      for (int i = 0; i < 32; ++i){
        int k = koff + i * 32 + khi;
        short8 a = *(const short8*)(pA + i * 32 + khi);
        r0 = __builtin_amdgcn_mfma_f32_16x16x32_bf16(a, ldsB(lo, k), r0, 0,0,0);
        r1 = __builtin_amdgcn_mfma_f32_16x16x32_bf16(a, ldsB(16 + lo, k), r1, 0,0,0);
      }
    }
  };

  f32x4 xn0, xn1;
  float creg = 0.f;
  if (lay == 0){ xn0 = f32x4{bv0,bv0,bv0,bv0}; xn1 = f32x4{bv1,bv1,bv1,bv1};
                 mm(x, 0, xn0, xn1); }

  for (int s = 0; s <= 257; ++s){
    const int t = lay ? (s - 2) : s;
    const bool act = (t >= 0) && (t < T_LEN);
    if (act){
      f32x4 a0 = xn0, a1 = xn1;
      if (t > 0){
        const u16* Asrc = lay ? (hB + (size_t)(t - 1) * BH)
                              : (hA + (size_t)(s - 1) * BH);
        mm(Asrc, 1024, a0, a1);
      }
      const int r0i = mt * 16 + hi * 4;
      if (nw == 0){
        *(f32x4*)&smT[lo * 68 + r0i] = a0;
        *(f32x4*)&smT[(16 + lo) * 68 + r0i] = a1;
      } else {
        *(f32x4*)&restT[lo * 68 + r0i] = a0;
        *(f32x4*)&restT[(16 + lo) * 68 + r0i] = a1;
      }
      __syncthreads();
      {
        const int r = tid >> 3, j = tid & 7;
        const int n = (wg & 127) >> 3;
        float m1 = -1e30f, m2 = -1e30f;
        float l1[16], l2[16];
        #pragma unroll
        for (int i = 0; i < 16; ++i){
          l1[i] = smT[i * 68 + r]; l2[i] = smT[(16 + i) * 68 + r];
          m1 = fmaxf(m1, l1[i]);   m2 = fmaxf(m2, l2[i]);
        }
        float s1 = 0.f, s2 = 0.f, cu1 = 0.f, cu2 = 0.f;
        #pragma unroll
        for (int i = 0; i < 16; ++i){
          float e1 = __expf(l1[i] - m1), e2 = __expf(l2[i] - m2);
          s1 += e1; s2 += e2;
          if (i <= n){ cu1 += e1; cu2 += e2; }
        }
        const float cin = 1.f - cu1 / s1;
        const float cf  = cu2 / s2;
        const float ov  = cf * cin;
        const float og = restT[j * 68 + r];
        const float ce = restT[(8 + j) * 68 + r];
        const float ig = restT[(16 + j) * 68 + r];
        const float fg = restT[(24 + j) * 68 + r];
        const float ogv = 1.f / (1.f + __expf(-og));
        const float inv = 1.f / (1.f + __expf(-ig));
        const float fgv = 1.f / (1.f + __expf(-fg));
        const float cev = tanhf(ce);
        if (t == 0) creg = 0.f;
        const float fga = fgv * ov + (cf - ov);
        const float iga = inv * ov + (cin - ov);
        const float cy  = fga * creg + iga * cev;
        creg = cy;
        const float hy = ogv * tanhf(cy);
        hStage[r * 8 + j] = f2bf(hy);
        if (lay) oStage[r * 8 + j] = hy;
      }
      __syncthreads();
      // coalesced handoff: wave0 -> h (volatile 16B/lane); waves 1-2 -> out
      if (tid < 64){
        int4v hv = *(const int4v*)&hStage[tid * 8];
        u16* dst = (lay ? hB : hA) + (size_t)t * BH + tid * HID + E0;
        *(volatile int4v*)dst = hv;
      } else if (lay && tid < 192){
        int w = tid - 64;
        int r = w >> 1, half = w & 1;
        f32x4 ov4 = *(const f32x4*)&oStage[r * 8 + half * 4];
        *(f32x4*)&out[((size_t)t * BATCH + r) * HID + E0 + half * 4] = ov4;
      }
    }
    // ---- arrival: drain h stores, then 4B slot store ----
    asm volatile("s_waitcnt vmcnt(0)" ::: "memory");
    __syncthreads();
    if (tid == 0) *(volatile unsigned*)&slots[wg] = (unsigned)(s + 1);
    // ---- slack: next epoch's ih-product (LDS/L2 weights) ----
    if (lay == 0){
      if (s <= T_LEN - 2){
        xn0 = f32x4{bv0,bv0,bv0,bv0}; xn1 = f32x4{bv1,bv1,bv1,bv1};
        mm(x + (size_t)(s + 1) * BH, 0, xn0, xn1);
      }
    } else {
      if (s >= 1 && s <= T_LEN){
        xn0 = f32x4{bv0,bv0,bv0,bv0}; xn1 = f32x4{bv1,bv1,bv1,bv1};
        mm(hA + (size_t)(s - 1) * BH, 0, xn0, xn1);
      }
    }
    // ---- barrier: all spins are whole-wave uniform + VALU-burn ----
    if (s < 257){
      const unsigned tg = (unsigned)(s + 1);
      if (wg == 0){
        if (wave == 0){
          // master: uniform 16B/lane scan of all 256 packed slots
          const volatile int4v* sp = (const volatile int4v*)&slots[lane * 4];
          for (;;){
            int4v v = *sp;
            int ok = ((unsigned)v[0] >= tg) & ((unsigned)v[1] >= tg) &
                     ((unsigned)v[2] >= tg) & ((unsigned)v[3] >= tg);
            if (__all(ok)) break;
            burn();
          }
          if (lane == 0){
            *(volatile unsigned*)flag = tg;       // release other WGs
            *(volatile unsigned*)&lflag = tg;     // release waves 1-7 here
          }
        } else {
          while (*(volatile const unsigned*)&lflag < tg) burn();  // <- wave 0
        }
      } else {
        if (wave == 0){
          // whole-wave uniform poll of the single flag word (1 txn/wave)
          while (*(volatile const unsigned*)flag < tg) burn();    // <- WG 0
          if (lane == 0) *(volatile unsigned*)&lflag = tg;
        } else {
          while (*(volatile const unsigned*)&lflag < tg) burn();  // <- wave 0
        }
      }
      __syncthreads();
    }
  }
}

// ---- launch -----------------------------------------------------------------

extern "C" void kernel_launch(void* const* d_in, const int* in_sizes, int n_in,
                              void* d_out, int out_size, void* d_ws, size_t ws_size,
                              hipStream_t stream)
{
  (void)in_sizes; (void)n_in; (void)out_size; (void)ws_size;
  const int*   tokens = (const int*)d_in[0];
  const float* emb    = (const float*)d_in[1];
  const float* Wih0   = (const float*)d_in[2];
  const float* bih0   = (const float*)d_in[3];
  const float* Whh0   = (const float*)d_in[4];
  const float* bhh0   = (const float*)d_in[5];
  const float* Wih1   = (const float*)d_in[6];
  const float* bih1   = (const float*)d_in[7];
  const float* Whh1   = (const float*)d_in[8];
  const float* bhh1   = (const float*)d_in[9];
  float* out = (float*)d_out;

  char* ws = (char*)d_ws;
  u16*   Wt0    = (u16*)(ws);                     // 16,908,288
  u16*   Wt1    = (u16*)(ws + 16908288);          // 16,908,288
  u16*   x      = (u16*)(ws + 33816576);          // 33,554,432
  u16*   hA     = (u16*)(ws + 67371008);          // 33,554,432 (h1 full history)
  u16*   hB     = (u16*)(ws + 100925440);         // 33,554,432 (h2 full history)
  float* bias0  = (float*)(ws + 134479872);       // 16,512
  float* bias1  = (float*)(ws + 134496384);       // 16,512
  unsigned* slots = (unsigned*)(ws + 134512896);  // 1,024 (256 x 4B packed)
  unsigned* flag  = (unsigned*)(ws + 134513920);  // 128
  // total 134,514,048 bytes

  repackW<<<dim3(64,129), dim3(32,32), 0, stream>>>(Wih0, Whh0, Wt0);
  repackW<<<dim3(64,129), dim3(32,32), 0, stream>>>(Wih1, Whh1, Wt1);
  gatherX<<<16384, 256, 0, stream>>>(tokens, emb, x, out + 16777216);
  biasK<<<17, 256, 0, stream>>>(bih0, bhh0, bih1, bhh1, bias0, bias1);
  hipMemsetAsync(slots, 0, 2048, stream);

  persist<<<NWG, 512, 0, stream>>>(Wt0, Wt1, bias0, bias1, x, hA, hB,
                                   out, slots, flag);
}

// Round 13
// 7795.541 us; speedup vs baseline: 1.3660x; 1.2553x over previous
//
#include <hip/hip_runtime.h>

typedef __attribute__((ext_vector_type(8))) short short8;
typedef __attribute__((ext_vector_type(4))) float f32x4;
typedef __attribute__((ext_vector_type(4))) int int4v;
typedef __attribute__((ext_vector_type(4))) unsigned short u16x4;
typedef unsigned short u16;

#define T_LEN 256
#define BATCH 64
#define HID   1024
#define GDIM  4128
#define BH    65536
#define NWG   256

__device__ __forceinline__ u16 f2bf(float f){
  unsigned u = __builtin_bit_cast(unsigned, f);
  return (u16)((u + 0x7fffu + ((u >> 16) & 1u)) >> 16);
}

// ---- prologue kernels -------------------------------------------------------

__global__ __launch_bounds__(1024) void repackW(const float* __restrict__ Wih,
                                                const float* __restrict__ Whh,
                                                u16* __restrict__ Wt)
{
  __shared__ float tile[32][33];
  int k = blockIdx.x * 32 + threadIdx.y;
  int c = blockIdx.y * 32 + threadIdx.x;
  float v = (k < 1024) ? Wih[(size_t)k * GDIM + c]
                       : Whh[(size_t)(k - 1024) * GDIM + c];
  tile[threadIdx.y][threadIdx.x] = v;
  __syncthreads();
  int c2 = blockIdx.y * 32 + threadIdx.y;
  int k2 = blockIdx.x * 32 + threadIdx.x;
  Wt[(size_t)c2 * 2048 + k2] = f2bf(tile[threadIdx.x][threadIdx.y]);
}

__global__ __launch_bounds__(256) void gatherX(const int* __restrict__ tokens,
                                               const float* __restrict__ emb,
                                               u16* __restrict__ x,
                                               float* __restrict__ maskout)
{
  int idx = blockIdx.x;
  int tok = tokens[idx];
  const f32x4* src = (const f32x4*)&emb[(size_t)tok * HID];
  f32x4 v = src[threadIdx.x];
  u16x4 o;
  #pragma unroll
  for (int j = 0; j < 4; ++j) o[j] = f2bf(v[j]);
  *(u16x4*)&x[(size_t)idx * HID + threadIdx.x * 4] = o;
  if (threadIdx.x == 0) maskout[idx] = (tok != 0) ? 1.0f : 0.0f;
}

__global__ __launch_bounds__(256) void biasK(const float* __restrict__ bih0, const float* __restrict__ bhh0,
                                             const float* __restrict__ bih1, const float* __restrict__ bhh1,
                                             float* __restrict__ bias0, float* __restrict__ bias1)
{
  int i = blockIdx.x * 256 + threadIdx.x;
  if (i < GDIM){ bias0[i] = bih0[i] + bhh0[i]; bias1[i] = bih1[i] + bhh1[i]; }
}

// ---- fused persistent kernel ------------------------------------------------
// Round-6 structure (best known: 8.19ms) with ONE change: coalesced h/out
// handoff via LDS stage + wave-local drain. 256 WGs x 512 thr, 1 WG/CU.
// WG w: lay = w>>7, owns h-elems E0..E0+7 (E0=(w&127)*8). Rest weights
// (32 cols x K=2048) LDS-resident; sm cols (0..31) from L2. Epoch s: L0 t=s,
// L1 t=s-2. Gates never leave the WG. ONE barrier/epoch: 4B slot store by
// tid0 (after wave-0-local vmcnt drain of the h stores); EVERY WG's wave-0
// busy-scans all 256 packed slots (1 x 16B load/lane).
__global__ __launch_bounds__(512, 1) void persist(
    const u16* __restrict__ Wt0, const u16* __restrict__ Wt1,
    const float* __restrict__ bias0, const float* __restrict__ bias1,
    const u16* __restrict__ x, u16* __restrict__ hA, u16* __restrict__ hB,
    float* __restrict__ out, unsigned* __restrict__ slots)
{
  __shared__ __align__(16) u16 Ws[32 * 2048];      // 128KB rest weights (ih+hh)
  __shared__ __align__(16) float smT[32 * 68];     // sm logits, [col][row]
  __shared__ __align__(16) float restT[32 * 68];   // rest gates, [col][row]
  __shared__ __align__(16) u16 hStage[64 * 8];     // bf16 h, [row][elem]
  __shared__ __align__(16) float oStage[64 * 8];   // f32 h2, [row][elem]

  const int wg = blockIdx.x, tid = threadIdx.x;
  const int lane = tid & 63, wave = tid >> 6;
  const int lo = lane & 15, hi = lane >> 4, khi = hi * 8;
  const int mt = wave >> 1, nw = wave & 1;         // 4 M-tiles x 2 tile-groups
  const int row = mt * 16 + lo;
  const int lay = wg >> 7;
  const int E0 = (wg & 127) * 8;
  const u16* Wt = lay ? Wt1 : Wt0;
  const float* bias = lay ? bias1 : bias0;

  auto gcol = [&](int c){ return 32 + (c >> 3) * 1024 + E0 + (c & 7); };

  // one-time staging: 32 rest cols x K=2048, XOR-swizzled (16B-preserving)
  for (int i = tid; i < 32 * 256; i += 512){
    int c = i >> 8, ck = (i & 255) << 3;
    *(int4v*)&Ws[c * 2048 + (ck ^ ((c & 7) << 3))] =
        *(const int4v*)&Wt[(size_t)gcol(c) * 2048 + ck];
  }

  // per-wave tiles: nw=0 -> sm cols {lo,16+lo} (global B); nw=1 -> rest local
  float bv0, bv1;
  const u16 *gB0 = nullptr, *gB1 = nullptr;
  if (nw == 0){
    bv0 = bias[lo]; bv1 = bias[16 + lo];
    gB0 = Wt + (size_t)lo * 2048;
    gB1 = Wt + (size_t)(16 + lo) * 2048;
  } else {
    bv0 = bias[gcol(lo)]; bv1 = bias[gcol(16 + lo)];
  }
  __syncthreads();

  auto ldsB = [&](int c, int k)->short8 {
    return *(const short8*)&Ws[c * 2048 + (k ^ ((c & 7) << 3))];
  };

  f32x4 xn0, xn1;                    // slack accumulators (bias + ih-part)
  auto slack_mm = [&](const u16* Asrc){
    f32x4 s0 = {bv0,bv0,bv0,bv0}, s1 = {bv1,bv1,bv1,bv1};
    const u16* pA = Asrc + (size_t)row * HID;
    if (nw == 0){
      #pragma unroll 1
      for (int blk = 0; blk < 4; ++blk){
        short8 A[8], B0[8], B1[8];
        #pragma unroll
        for (int i = 0; i < 8; ++i){
          int k = (blk * 8 + i) * 32 + khi;
          A[i]  = *(const short8*)(pA + k);
          B0[i] = *(const short8*)(gB0 + k);
          B1[i] = *(const short8*)(gB1 + k);
        }
        #pragma unroll
        for (int i = 0; i < 8; ++i){
          s0 = __builtin_amdgcn_mfma_f32_16x16x32_bf16(A[i], B0[i], s0, 0,0,0);
          s1 = __builtin_amdgcn_mfma_f32_16x16x32_bf16(A[i], B1[i], s1, 0,0,0);
        }
      }
    } else {
      #pragma unroll 1
      for (int blk = 0; blk < 4; ++blk){
        short8 A[8];
        #pragma unroll
        for (int i = 0; i < 8; ++i)
          A[i] = *(const short8*)(pA + (blk * 8 + i) * 32 + khi);
        #pragma unroll
        for (int i = 0; i < 8; ++i){
          int k = (blk * 8 + i) * 32 + khi;
          s0 = __builtin_amdgcn_mfma_f32_16x16x32_bf16(A[i], ldsB(lo, k), s0, 0,0,0);
          s1 = __builtin_amdgcn_mfma_f32_16x16x32_bf16(A[i], ldsB(16 + lo, k), s1, 0,0,0);
        }
      }
    }
    xn0 = s0; xn1 = s1;
  };

  float creg = 0.f;                  // c-state: one scalar per thread
  if (lay == 0) slack_mm(x);         // xn for t=0

  for (int s = 0; s <= 257; ++s){
    const int t = lay ? (s - 2) : s;
    const bool act = (t >= 0) && (t < T_LEN);
    if (act){
      f32x4 a0 = xn0, a1 = xn1;
      if (t > 0){
        const u16* Asrc = lay ? (hB + (size_t)(t - 1) * BH)
                              : (hA + (size_t)(s - 1) * BH);
        const u16* pA = Asrc + (size_t)row * HID;
        if (nw == 0){
          #pragma unroll 1
          for (int blk = 0; blk < 4; ++blk){
            short8 A[8], B0[8], B1[8];
            #pragma unroll
            for (int i = 0; i < 8; ++i){
              int k = (blk * 8 + i) * 32 + khi;
              A[i]  = *(const short8*)(pA + k);
              B0[i] = *(const short8*)(gB0 + 1024 + k);
              B1[i] = *(const short8*)(gB1 + 1024 + k);
            }
            #pragma unroll
            for (int i = 0; i < 8; ++i){
              a0 = __builtin_amdgcn_mfma_f32_16x16x32_bf16(A[i], B0[i], a0, 0,0,0);
              a1 = __builtin_amdgcn_mfma_f32_16x16x32_bf16(A[i], B1[i], a1, 0,0,0);
            }
          }
        } else {
          #pragma unroll 1
          for (int blk = 0; blk < 4; ++blk){
            short8 A[8];
            #pragma unroll
            for (int i = 0; i < 8; ++i)
              A[i] = *(const short8*)(pA + (blk * 8 + i) * 32 + khi);
            #pragma unroll
            for (int i = 0; i < 8; ++i){
              int k = (blk * 8 + i) * 32 + khi;
              a0 = __builtin_amdgcn_mfma_f32_16x16x32_bf16(A[i], ldsB(lo, 1024 + k), a0, 0,0,0);
              a1 = __builtin_amdgcn_mfma_f32_16x16x32_bf16(A[i], ldsB(16 + lo, 1024 + k), a1, 0,0,0);
            }
          }
        }
      }
      // transpose acc -> per-row layout (C/D: col=lane&15, row=(lane>>4)*4+j)
      const int r0i = mt * 16 + hi * 4;
      if (nw == 0){
        *(f32x4*)&smT[lo * 68 + r0i] = a0;
        *(f32x4*)&smT[(16 + lo) * 68 + r0i] = a1;
      } else {
        *(f32x4*)&restT[lo * 68 + r0i] = a0;
        *(f32x4*)&restT[(16 + lo) * 68 + r0i] = a1;
      }
      __syncthreads();
      // gating: thread -> (row r, elem E0+j); results staged in LDS
      {
        const int r = tid >> 3, j = tid & 7;
        const int n = (wg & 127) >> 3;
        float m1 = -1e30f, m2 = -1e30f;
        float l1[16], l2[16];
        #pragma unroll
        for (int i = 0; i < 16; ++i){
          l1[i] = smT[i * 68 + r]; l2[i] = smT[(16 + i) * 68 + r];
          m1 = fmaxf(m1, l1[i]);   m2 = fmaxf(m2, l2[i]);
        }
        float s1 = 0.f, s2 = 0.f, cu1 = 0.f, cu2 = 0.f;
        #pragma unroll
        for (int i = 0; i < 16; ++i){
          float e1 = __expf(l1[i] - m1), e2 = __expf(l2[i] - m2);
          s1 += e1; s2 += e2;
          if (i <= n){ cu1 += e1; cu2 += e2; }
        }
        const float cin = 1.f - cu1 / s1;
        const float cf  = cu2 / s2;
        const float ov  = cf * cin;
        const float og = restT[j * 68 + r];
        const float ce = restT[(8 + j) * 68 + r];
        const float ig = restT[(16 + j) * 68 + r];
        const float fg = restT[(24 + j) * 68 + r];
        const float ogv = 1.f / (1.f + __expf(-og));
        const float inv = 1.f / (1.f + __expf(-ig));
        const float fgv = 1.f / (1.f + __expf(-fg));
        const float cev = tanhf(ce);
        if (t == 0) creg = 0.f;
        const float fga = fgv * ov + (cf - ov);
        const float iga = inv * ov + (cin - ov);
        const float cy  = fga * creg + iga * cev;
        creg = cy;
        const float hy = ogv * tanhf(cy);
        hStage[r * 8 + j] = f2bf(hy);
        if (lay) oStage[r * 8 + j] = hy;
      }
      __syncthreads();
      // coalesced handoff: wave0 -> h (volatile 16B/lane) + WAVE-LOCAL drain
      // + slot store (tid0 is in wave0; s_waitcnt is per-wave). Waves 1-2 ->
      // out, NO drain (no device consumer). No extra __syncthreads.
      if (tid < 64){
        int4v hv = *(const int4v*)&hStage[tid * 8];
        u16* dst = (lay ? hB : hA) + (size_t)t * BH + tid * HID + E0;
        *(volatile int4v*)dst = hv;
        asm volatile("s_waitcnt vmcnt(0)" ::: "memory");
        if (tid == 0) *(volatile unsigned*)&slots[wg] = (unsigned)(s + 1);
      } else if (lay && tid < 192){
        int w = tid - 64;                       // 0..127
        int r = w >> 1, half = w & 1;
        f32x4 ov4 = *(const f32x4*)&oStage[r * 8 + half * 4];
        *(f32x4*)&out[((size_t)t * BATCH + r) * HID + E0 + half * 4] = ov4;
      }
    } else {
      if (tid == 0) *(volatile unsigned*)&slots[wg] = (unsigned)(s + 1);
    }
    // ---- slack: next epoch's ih-product (LDS/L2 weights) ----
    if (lay == 0){
      if (s <= T_LEN - 2) slack_mm(x + (size_t)(s + 1) * BH);
    } else {
      if (s >= 1 && s <= T_LEN) slack_mm(hA + (size_t)(s - 1) * BH);
    }
    // ---- barrier: every WG's wave-0 busy-scans all 256 packed slots ----
    if (s < 257){
      const unsigned tg = (unsigned)(s + 1);
      if (tid < 64){
        const volatile int4v* sp = (const volatile int4v*)&slots[tid * 4];
        for (;;){
          int4v v = *sp;
          int ok = ((unsigned)v[0] >= tg) & ((unsigned)v[1] >= tg) &
                   ((unsigned)v[2] >= tg) & ((unsigned)v[3] >= tg);
          if (__all(ok)) break;
        }
      }
      __syncthreads();
    }
  }
}

// ---- launch -----------------------------------------------------------------

extern "C" void kernel_launch(void* const* d_in, const int* in_sizes, int n_in,
                              void* d_out, int out_size, void* d_ws, size_t ws_size,
                              hipStream_t stream)
{
  (void)in_sizes; (void)n_in; (void)out_size; (void)ws_size;
  const int*   tokens = (const int*)d_in[0];
  const float* emb    = (const float*)d_in[1];
  const float* Wih0   = (const float*)d_in[2];
  const float* bih0   = (const float*)d_in[3];
  const float* Whh0   = (const float*)d_in[4];
  const float* bhh0   = (const float*)d_in[5];
  const float* Wih1   = (const float*)d_in[6];
  const float* bih1   = (const float*)d_in[7];
  const float* Whh1   = (const float*)d_in[8];
  const float* bhh1   = (const float*)d_in[9];
  float* out = (float*)d_out;

  char* ws = (char*)d_ws;
  u16*   Wt0    = (u16*)(ws);                     // 16,908,288
  u16*   Wt1    = (u16*)(ws + 16908288);          // 16,908,288
  u16*   x      = (u16*)(ws + 33816576);          // 33,554,432
  u16*   hA     = (u16*)(ws + 67371008);          // 33,554,432 (h1 full history)
  u16*   hB     = (u16*)(ws + 100925440);         // 33,554,432 (h2 full history)
  float* bias0  = (float*)(ws + 134479872);       // 16,512
  float* bias1  = (float*)(ws + 134496384);       // 16,512
  unsigned* slots = (unsigned*)(ws + 134512896);  // 1,024 (256 x 4B packed)
  // total 134,513,920 bytes

  repackW<<<dim3(64,129), dim3(32,32), 0, stream>>>(Wih0, Whh0, Wt0);
  repackW<<<dim3(64,129), dim3(32,32), 0, stream>>>(Wih1, Whh1, Wt1);
  gatherX<<<16384, 256, 0, stream>>>(tokens, emb, x, out + 16777216);
  biasK<<<17, 256, 0, stream>>>(bih0, bhh0, bih1, bhh1, bias0, bias1);
  hipMemsetAsync(slots, 0, 1024, stream);

  persist<<<NWG, 512, 0, stream>>>(Wt0, Wt1, bias0, bias1, x, hA, hB,
                                   out, slots);
}